// Round 1
// baseline (933.666 us; speedup 1.0000x reference)
//
#include <hip/hip_runtime.h>
#include <cmath>

#define B_ 4
#define T_ 8192
#define C_ 256
#define E_ 8
#define M_ (B_*T_)

typedef __bf16 bf16x8 __attribute__((ext_vector_type(8)));
typedef float  f32x4  __attribute__((ext_vector_type(4)));

static __device__ __forceinline__ unsigned short f2bf(float f) {
    union { float fv; unsigned u; } v; v.fv = f;
    unsigned r = v.u + 0x7FFFu + ((v.u >> 16) & 1u);
    return (unsigned short)(r >> 16);
}

static __device__ __forceinline__ float gelu_f(float x) {
    return 0.5f * x * (1.0f + erff(x * 0.7071067811865476f));
}

static __device__ __forceinline__ f32x4 mfma16(bf16x8 a, bf16x8 b, f32x4 c) {
    return __builtin_amdgcn_mfma_f32_16x16x32_bf16(a, b, c, 0, 0, 0);
}

// ---------------- prep kernels ----------------

__global__ void k_cvt_x(const float* __restrict__ x, unsigned short* __restrict__ xb) {
    int i = (blockIdx.x * 256 + threadIdx.x) * 4;
    float4 v = *reinterpret_cast<const float4*>(x + i);
    ushort4 o;
    o.x = f2bf(v.x); o.y = f2bf(v.y); o.z = f2bf(v.z); o.w = f2bf(v.w);
    *reinterpret_cast<ushort4*>(xb + i) = o;
}

// W1xT[e][c][k] = W1[e][k][c], k in [0,256) (the x-block rows), bf16
__global__ void k_w1t(const float* __restrict__ W1, unsigned short* __restrict__ w1t) {
    int e = blockIdx.x >> 8, c = blockIdx.x & 255, k = threadIdx.x;
    w1t[(((e << 8) + c) << 8) + k] = f2bf(W1[((size_t)e * 1024 + k) * 256 + c]);
}

// W2T[e][f][c] = W2[e][c][f], bf16
__global__ void k_w2t(const float* __restrict__ W2, unsigned short* __restrict__ w2t) {
    int e = blockIdx.x >> 8, f = blockIdx.x & 255, c = threadIdx.x;
    w2t[(((e << 8) + f) << 8) + c] = f2bf(W2[(((e << 8) + c) << 8) + f]);
}

// v2[e][c] = sum_f W2[e,c,f]*We[e,f];  c2[e] = sum_f b2[e,f]*We[e,f] + be[e]
__global__ void k_v2(const float* __restrict__ W2, const float* __restrict__ We,
                     const float* __restrict__ b2, const float* __restrict__ be,
                     float* __restrict__ v2, float* __restrict__ c2) {
    __shared__ float sm[4];
    int e = blockIdx.x >> 8, c = blockIdx.x & 255, f = threadIdx.x;
    float wef = We[(e << 8) + f];
    float v = W2[((((e << 8) + c) << 8)) + f] * wef;
#pragma unroll
    for (int m = 32; m >= 1; m >>= 1) v += __shfl_xor(v, m);
    if ((f & 63) == 0) sm[f >> 6] = v;
    __syncthreads();
    if (f == 0) v2[(e << 8) + c] = sm[0] + sm[1] + sm[2] + sm[3];
    if (c == 0) {
        __syncthreads();
        float u = b2[(e << 8) + f] * wef;
#pragma unroll
        for (int m = 32; m >= 1; m >>= 1) u += __shfl_xor(u, m);
        if ((f & 63) == 0) sm[f >> 6] = u;
        __syncthreads();
        if (f == 0) c2[e] = sm[0] + sm[1] + sm[2] + sm[3] + be[e];
    }
}

// ---------------- LN + masked stats ----------------

__global__ void k_stats(const float* __restrict__ x, const int* __restrict__ mask,
                        const float* __restrict__ lnw, const float* __restrict__ lnb,
                        float* __restrict__ S1, float* __restrict__ S2, float* __restrict__ ncnt) {
    int b = blockIdx.x >> 4;
    int chunk = blockIdx.x & 15;
    int wid = threadIdx.x >> 6, lane = threadIdx.x & 63;
    int c0 = lane << 2;
    float4 w4 = *reinterpret_cast<const float4*>(lnw + c0);
    float4 b4 = *reinterpret_cast<const float4*>(lnb + c0);
    float a1[4] = {0,0,0,0}, a2[4] = {0,0,0,0};
    int cnt = 0;
    int tbase = chunk * 512;
    for (int r = wid; r < 512; r += 4) {
        int row = b * T_ + tbase + r;
        float4 xv = *reinterpret_cast<const float4*>(x + (size_t)row * C_ + c0);
        float s1 = xv.x + xv.y + xv.z + xv.w;
        float s2 = xv.x*xv.x + xv.y*xv.y + xv.z*xv.z + xv.w*xv.w;
#pragma unroll
        for (int m = 1; m < 64; m <<= 1) { s1 += __shfl_xor(s1, m); s2 += __shfl_xor(s2, m); }
        if (mask[row]) {
            float mu = s1 * (1.f / C_);
            float var = s2 * (1.f / C_) - mu * mu;
            float rs = rsqrtf(var + 1e-5f);
            float hv;
            hv = (xv.x - mu) * rs * w4.x + b4.x; a1[0] += hv; a2[0] += hv * hv;
            hv = (xv.y - mu) * rs * w4.y + b4.y; a1[1] += hv; a2[1] += hv * hv;
            hv = (xv.z - mu) * rs * w4.z + b4.z; a1[2] += hv; a2[2] += hv * hv;
            hv = (xv.w - mu) * rs * w4.w + b4.w; a1[3] += hv; a2[3] += hv * hv;
            cnt++;
        }
    }
    __shared__ float red[4][256];
    __shared__ int rc[4];
#pragma unroll
    for (int j = 0; j < 4; j++) red[wid][c0 + j] = a1[j];
    if (lane == 0) rc[wid] = cnt;
    __syncthreads();
    int ch = threadIdx.x;
    float s = red[0][ch] + red[1][ch] + red[2][ch] + red[3][ch];
    atomicAdd(&S1[(b << 8) + ch], s);
    if (threadIdx.x == 0) atomicAdd(&ncnt[b], (float)(rc[0] + rc[1] + rc[2] + rc[3]));
    __syncthreads();
#pragma unroll
    for (int j = 0; j < 4; j++) red[wid][c0 + j] = a2[j];
    __syncthreads();
    s = red[0][ch] + red[1][ch] + red[2][ch] + red[3][ch];
    atomicAdd(&S2[(b << 8) + ch], s);
}

__global__ void k_stats_fin(const float* __restrict__ S1, const float* __restrict__ S2,
                            const float* __restrict__ ncnt, float* __restrict__ stats) {
    int b = blockIdx.x, c = threadIdx.x;
    float n = fmaxf(ncnt[b], 1.f);
    float mean = S1[(b << 8) + c] / n;
    float var_b = fmaxf(S2[(b << 8) + c] / n - mean * mean, 0.f);
    float var_u = (n > 1.f) ? (var_b * (n / fmaxf(n - 1.f, 1e-9f))) : var_b;
    float std_u = fmaxf(sqrtf(var_u), 1e-9f);
    stats[b * 768 + 0 * 256 + c] = mean;
    stats[b * 768 + 1 * 256 + c] = std_u;
    stats[b * 768 + 2 * 256 + c] = var_u;
}

// bias_be[b,e,c] = b1[e,c] + sum_j mean_j*W1[e,256+j,c] + std_j*W1[e,512+j,c] + var_j*W1[e,768+j,c]
__global__ void k_bias(const float* __restrict__ W1, const float* __restrict__ b1,
                       const float* __restrict__ stats, float* __restrict__ bias) {
    int b = blockIdx.x >> 3, e = blockIdx.x & 7, c = threadIdx.x;
    __shared__ float sm[768];
    for (int i = threadIdx.x; i < 768; i += 256) sm[i] = stats[b * 768 + i];
    __syncthreads();
    const float* w = W1 + (size_t)e * 1024 * 256;
    float acc = b1[(e << 8) + c];
#pragma unroll 4
    for (int j = 0; j < 256; j++) {
        acc += sm[j]       * w[(256 + j) * 256 + c];
        acc += sm[256 + j] * w[(512 + j) * 256 + c];
        acc += sm[512 + j] * w[(768 + j) * 256 + c];
    }
    bias[((b << 3) + e) * 256 + c] = acc;
}

// ---------------- energies: GEMM1 + gelu + dot(v2) ----------------

__global__ __launch_bounds__(256, 2) void k_energy(
    const unsigned short* __restrict__ xb, const unsigned short* __restrict__ w1t,
    const float* __restrict__ bias, const float* __restrict__ v2,
    const float* __restrict__ c2, float* __restrict__ energy) {
    int row0 = blockIdx.x << 6;
    int b = row0 >> 13;
    int wid = threadIdx.x >> 6, lane = threadIdx.x & 63;
    int rlo = lane & 15, khi = lane >> 4;
    const unsigned short* arow = xb + (size_t)(row0 + (wid << 4) + rlo) * C_ + (khi << 3);
    for (int e = 0; e < E_; e++) {
        const float* bre = bias + ((b << 3) + e) * C_;
        f32x4 acc[16];
#pragma unroll
        for (int n = 0; n < 16; n++) {
            float bv = bre[(n << 4) + rlo];
#pragma unroll
            for (int i = 0; i < 4; i++) acc[n][i] = bv;
        }
        const unsigned short* wb = w1t + (e << 16) + rlo * C_ + (khi << 3);
#pragma unroll
        for (int kk = 0; kk < 8; kk++) {
            bf16x8 a = *reinterpret_cast<const bf16x8*>(arow + (kk << 5));
#pragma unroll
            for (int n = 0; n < 16; n++) {
                bf16x8 bf = *reinterpret_cast<const bf16x8*>(wb + ((n << 4) * C_) + (kk << 5));
                acc[n] = mfma16(a, bf, acc[n]);
            }
        }
        float ep[4] = {0,0,0,0};
#pragma unroll
        for (int n = 0; n < 16; n++) {
            float vv = v2[(e << 8) + (n << 4) + rlo];
#pragma unroll
            for (int i = 0; i < 4; i++) ep[i] += gelu_f(acc[n][i]) * vv;
        }
#pragma unroll
        for (int m = 1; m < 16; m <<= 1) {
#pragma unroll
            for (int i = 0; i < 4; i++) ep[i] += __shfl_xor(ep[i], m);
        }
        if (rlo == 0) {
            float cc = c2[e];
#pragma unroll
            for (int i = 0; i < 4; i++)
                energy[(size_t)(row0 + (wid << 4) + (khi << 2) + i) * E_ + e] = ep[i] + cc;
        }
    }
}

// ---------------- output: softmax + GEMM1 + gelu + scale + GEMM2 ----------------

__global__ __launch_bounds__(256, 2) void k_out(
    const unsigned short* __restrict__ xb, const unsigned short* __restrict__ w1t,
    const unsigned short* __restrict__ w2t, const float* __restrict__ bias,
    const float* __restrict__ energy, const int* __restrict__ mask,
    const float* __restrict__ b2, const float* __restrict__ log_beta,
    const float* __restrict__ prior, float* __restrict__ out) {
    __shared__ float probs_s[64][8];
    __shared__ float b2_s[8][256];
    __shared__ unsigned short h1_s[4][4096];
    int row0 = blockIdx.x << 6;
    int b = row0 >> 13;
    int tid = threadIdx.x;
    for (int i = tid; i < 2048; i += 256) (&b2_s[0][0])[i] = b2[i];
    if (tid < 64) {
        int row = row0 + tid;
        float beta = expf(log_beta[0]);
        float nb[8]; float mx = -3.4e38f;
#pragma unroll
        for (int e = 0; e < 8; e++) {
            nb[e] = -beta * (energy[(size_t)row * 8 + e] + prior[e]);
            mx = fmaxf(mx, nb[e]);
        }
        float s = 0.f; float pe[8];
#pragma unroll
        for (int e = 0; e < 8; e++) { pe[e] = expf(nb[e] - mx); s += pe[e]; }
        float inv = mask[row] ? (1.f / s) : 0.f;
#pragma unroll
        for (int e = 0; e < 8; e++) probs_s[tid][e] = pe[e] * inv;
    }
    __syncthreads();
    int wid = tid >> 6, lane = tid & 63;
    int rlo = lane & 15, khi = lane >> 4;
    unsigned short* h1w = h1_s[wid];
    const unsigned short* arow = xb + (size_t)(row0 + (wid << 4) + rlo) * C_ + (khi << 3);
    f32x4 acc2[16];
#pragma unroll
    for (int n = 0; n < 16; n++)
#pragma unroll
        for (int i = 0; i < 4; i++) acc2[n][i] = 0.f;

    for (int e = 0; e < E_; e++) {
        const float* bre = bias + ((b << 3) + e) * C_;
        f32x4 acc1[16];
#pragma unroll
        for (int n = 0; n < 16; n++) {
            float bv = bre[(n << 4) + rlo];
#pragma unroll
            for (int i = 0; i < 4; i++) acc1[n][i] = bv;
        }
        const unsigned short* wb = w1t + (e << 16) + rlo * C_ + (khi << 3);
#pragma unroll
        for (int kk = 0; kk < 8; kk++) {
            bf16x8 a = *reinterpret_cast<const bf16x8*>(arow + (kk << 5));
#pragma unroll
            for (int n = 0; n < 16; n++) {
                bf16x8 bf = *reinterpret_cast<const bf16x8*>(wb + ((n << 4) * C_) + (kk << 5));
                acc1[n] = mfma16(a, bf, acc1[n]);
            }
        }
        float pv[4];
#pragma unroll
        for (int i = 0; i < 4; i++) pv[i] = probs_s[(wid << 4) + (khi << 2) + i][e];
        // scaled gelu(h1) -> LDS (same-wave slice, XOR-swizzled rows)
#pragma unroll
        for (int n = 0; n < 16; n++) {
#pragma unroll
            for (int i = 0; i < 4; i++) {
                int row_l = (khi << 2) + i;
                int col = (n << 4) + rlo;
                int byteoff = ((row_l << 9) + (col << 1)) ^ ((row_l & 7) << 4);
                *reinterpret_cast<unsigned short*>(reinterpret_cast<char*>(h1w) + byteoff)
                    = f2bf(gelu_f(acc1[n][i]) * pv[i]);
            }
        }
        const unsigned short* wb2 = w2t + (e << 16) + rlo * C_ + (khi << 3);
#pragma unroll
        for (int kk = 0; kk < 8; kk++) {
            int byteoff = ((rlo << 9) + (kk << 6) + (khi << 4)) ^ ((rlo & 7) << 4);
            bf16x8 a2 = *reinterpret_cast<const bf16x8*>(reinterpret_cast<char*>(h1w) + byteoff);
#pragma unroll
            for (int n = 0; n < 16; n++) {
                bf16x8 bf = *reinterpret_cast<const bf16x8*>(wb2 + ((n << 4) * C_) + (kk << 5));
                acc2[n] = mfma16(a2, bf, acc2[n]);
            }
        }
    }
    // epilogue: + sum_e probs*b2, write (masked rows have probs==0 -> exact 0)
    float pr[4][8];
#pragma unroll
    for (int i = 0; i < 4; i++) {
        int row_l = (wid << 4) + (khi << 2) + i;
#pragma unroll
        for (int e = 0; e < 8; e++) pr[i][e] = probs_s[row_l][e];
    }
#pragma unroll
    for (int n = 0; n < 16; n++) {
        int col = (n << 4) + rlo;
        float bc[8];
#pragma unroll
        for (int e = 0; e < 8; e++) bc[e] = b2_s[e][col];
#pragma unroll
        for (int i = 0; i < 4; i++) {
            float o = acc2[n][i];
#pragma unroll
            for (int e = 0; e < 8; e++) o += pr[i][e] * bc[e];
            out[(size_t)(row0 + (wid << 4) + (khi << 2) + i) * C_ + col] = o;
        }
    }
}

// ---------------- launch ----------------

extern "C" void kernel_launch(void* const* d_in, const int* in_sizes, int n_in,
                              void* d_out, int out_size, void* d_ws, size_t ws_size,
                              hipStream_t stream) {
    (void)in_sizes; (void)n_in; (void)out_size; (void)ws_size;
    const float* x        = (const float*)d_in[0];
    const int*   mask     = (const int*)d_in[1];
    const float* lnw      = (const float*)d_in[2];
    const float* lnb      = (const float*)d_in[3];
    const float* W1       = (const float*)d_in[4];
    const float* b1       = (const float*)d_in[5];
    const float* W2       = (const float*)d_in[6];
    const float* b2       = (const float*)d_in[7];
    const float* We       = (const float*)d_in[8];
    const float* be       = (const float*)d_in[9];
    const float* log_beta = (const float*)d_in[10];
    const float* prior    = (const float*)d_in[11];
    float* out = (float*)d_out;
    char* ws = (char*)d_ws;

    constexpr size_t OFF_XB    = 0;                       // 32768*256*2 = 16 MB
    constexpr size_t OFF_W1T   = 16777216;                // 1 MB
    constexpr size_t OFF_W2T   = 17825792;                // 1 MB
    constexpr size_t OFF_V2    = 18874368;                // 8 KB
    constexpr size_t OFF_C2    = 18882560;                // 32 B
    constexpr size_t OFF_S1    = 18882592;                // 4 KB
    constexpr size_t OFF_S2    = 18886688;                // 4 KB
    constexpr size_t OFF_N     = 18890784;                // 16 B
    constexpr size_t OFF_STATS = 18890800;                // 12 KB
    constexpr size_t OFF_BIAS  = 18903088;                // 32 KB
    constexpr size_t OFF_EN    = 18935856;                // 1 MB

    unsigned short* xb  = (unsigned short*)(ws + OFF_XB);
    unsigned short* w1t = (unsigned short*)(ws + OFF_W1T);
    unsigned short* w2t = (unsigned short*)(ws + OFF_W2T);
    float* v2    = (float*)(ws + OFF_V2);
    float* c2    = (float*)(ws + OFF_C2);
    float* S1    = (float*)(ws + OFF_S1);
    float* S2    = (float*)(ws + OFF_S2);
    float* ncnt  = (float*)(ws + OFF_N);
    float* stats = (float*)(ws + OFF_STATS);
    float* bias  = (float*)(ws + OFF_BIAS);
    float* en    = (float*)(ws + OFF_EN);

    hipMemsetAsync(ws + OFF_S1, 0, 4096 + 4096 + 16, stream);

    k_cvt_x<<<8192, 256, 0, stream>>>(x, xb);
    k_w1t<<<2048, 256, 0, stream>>>(W1, w1t);
    k_w2t<<<2048, 256, 0, stream>>>(W2, w2t);
    k_v2<<<2048, 256, 0, stream>>>(W2, We, b2, be, v2, c2);
    k_stats<<<64, 256, 0, stream>>>(x, mask, lnw, lnb, S1, S2, ncnt);
    k_stats_fin<<<4, 256, 0, stream>>>(S1, S2, ncnt, stats);
    k_bias<<<32, 256, 0, stream>>>(W1, b1, stats, bias);
    k_energy<<<512, 256, 0, stream>>>(xb, w1t, bias, v2, c2, en);
    k_out<<<512, 256, 0, stream>>>(xb, w1t, w2t, bias, en, mask, b2, log_beta, prior, out);
}

// Round 2
// 352.755 us; speedup vs baseline: 2.6468x; 2.6468x over previous
//
#include <hip/hip_runtime.h>
#include <cmath>

#define B_ 4
#define T_ 8192
#define C_ 256
#define E_ 8
#define M_ (B_*T_)

typedef __bf16 bf16x8 __attribute__((ext_vector_type(8)));
typedef float  f32x4  __attribute__((ext_vector_type(4)));

typedef const __attribute__((address_space(1))) unsigned int* gas_t;
typedef __attribute__((address_space(3))) unsigned int* las_t;

static __device__ __forceinline__ unsigned short f2bf(float f) {
    union { float fv; unsigned u; } v; v.fv = f;
    unsigned r = v.u + 0x7FFFu + ((v.u >> 16) & 1u);
    return (unsigned short)(r >> 16);
}

// Abramowitz-Stegun 7.1.26: |err| <= 1.5e-7, ~13 VALU ops (v_rcp + v_exp HW instrs)
static __device__ __forceinline__ float fast_erf(float x) {
    float ax = fabsf(x);
    float t = __builtin_amdgcn_rcpf(1.0f + 0.3275911f * ax);
    float p = ((((1.061405429f * t - 1.453152027f) * t) + 1.421413741f) * t - 0.284496736f) * t + 0.254829592f;
    float y = 1.0f - p * t * __expf(-ax * ax);
    return copysignf(y, x);
}

static __device__ __forceinline__ float gelu_f(float x) {
    return 0.5f * x * (1.0f + fast_erf(x * 0.7071067811865476f));
}

static __device__ __forceinline__ f32x4 mfma16(bf16x8 a, bf16x8 b, f32x4 c) {
    return __builtin_amdgcn_mfma_f32_16x16x32_bf16(a, b, c, 0, 0, 0);
}

// cooperative 16KB chunk stage: [256 rows][32 k] bf16, row-major 64B rows.
// src points at w?t[e][row=0][k=kk*32]; global row stride = 256 ushorts.
static __device__ __forceinline__ void stage16k(const unsigned short* __restrict__ src,
                                                unsigned short* lds_base, int tid) {
#pragma unroll
    for (int i = 0; i < 4; i++) {
        int flat = i * 256 + tid;
        const unsigned short* gp = src + ((flat >> 2) << 8) + ((flat & 3) << 3);
        unsigned short* lp = lds_base + ((i * 256 + (tid & ~63)) << 3);
        __builtin_amdgcn_global_load_lds((gas_t)(const void*)gp, (las_t)(void*)lp, 16, 0, 0);
    }
}

// ---------------- prep kernels ----------------

__global__ void k_cvt_x(const float* __restrict__ x, unsigned short* __restrict__ xb) {
    int i = (blockIdx.x * 256 + threadIdx.x) * 4;
    float4 v = *reinterpret_cast<const float4*>(x + i);
    ushort4 o;
    o.x = f2bf(v.x); o.y = f2bf(v.y); o.z = f2bf(v.z); o.w = f2bf(v.w);
    *reinterpret_cast<ushort4*>(xb + i) = o;
}

// w1t[e][c][k] = W1[e][k][c], k in [0,256)  (tiled coalesced transpose)
__global__ void k_w1t(const float* __restrict__ W1, unsigned short* __restrict__ w1t) {
    __shared__ float tile[64][65];
    int e = blockIdx.x >> 4, kt = (blockIdx.x >> 2) & 3, ct = blockIdx.x & 3;
    int k0 = kt << 6, c0 = ct << 6;
    const float* src = W1 + ((size_t)e << 18) + ((size_t)k0 << 8) + c0;
    int r = threadIdx.x >> 6, col = threadIdx.x & 63;
#pragma unroll
    for (int i = 0; i < 16; i++)
        tile[r + i * 4][col] = src[(size_t)(r + i * 4) * 256 + col];
    __syncthreads();
    unsigned short* dst = w1t + (e << 16) + (c0 << 8) + k0;
#pragma unroll
    for (int i = 0; i < 16; i++)
        dst[(r + i * 4) * 256 + col] = f2bf(tile[col][r + i * 4]);
}

// w2t[e][f][c] = W2[e][c][f]
__global__ void k_w2t(const float* __restrict__ W2, unsigned short* __restrict__ w2t) {
    __shared__ float tile[64][65];
    int e = blockIdx.x >> 4, ct = (blockIdx.x >> 2) & 3, ft = blockIdx.x & 3;
    int c0 = ct << 6, f0 = ft << 6;
    const float* src = W2 + ((size_t)e << 16) + ((size_t)c0 << 8) + f0;
    int r = threadIdx.x >> 6, col = threadIdx.x & 63;
#pragma unroll
    for (int i = 0; i < 16; i++)
        tile[r + i * 4][col] = src[(size_t)(r + i * 4) * 256 + col];
    __syncthreads();
    unsigned short* dst = w2t + (e << 16) + (f0 << 8) + c0;
#pragma unroll
    for (int i = 0; i < 16; i++)
        dst[(r + i * 4) * 256 + col] = f2bf(tile[col][r + i * 4]);
}

// v2[e][c] = sum_f W2[e,c,f]*We[e,f];  c2[e] = sum_f b2[e,f]*We[e,f] + be[e]
__global__ void k_v2(const float* __restrict__ W2, const float* __restrict__ We,
                     const float* __restrict__ b2, const float* __restrict__ be,
                     float* __restrict__ v2, float* __restrict__ c2) {
    __shared__ float sm[4];
    int e = blockIdx.x >> 8, c = blockIdx.x & 255, f = threadIdx.x;
    float wef = We[(e << 8) + f];
    float v = W2[((((e << 8) + c) << 8)) + f] * wef;
#pragma unroll
    for (int m = 32; m >= 1; m >>= 1) v += __shfl_xor(v, m);
    if ((f & 63) == 0) sm[f >> 6] = v;
    __syncthreads();
    if (f == 0) v2[(e << 8) + c] = sm[0] + sm[1] + sm[2] + sm[3];
    if (c == 0) {
        __syncthreads();
        float u = b2[(e << 8) + f] * wef;
#pragma unroll
        for (int m = 32; m >= 1; m >>= 1) u += __shfl_xor(u, m);
        if ((f & 63) == 0) sm[f >> 6] = u;
        __syncthreads();
        if (f == 0) c2[e] = sm[0] + sm[1] + sm[2] + sm[3] + be[e];
    }
}

// ---------------- LN + masked stats ----------------

__global__ void k_stats(const float* __restrict__ x, const int* __restrict__ mask,
                        const float* __restrict__ lnw, const float* __restrict__ lnb,
                        float* __restrict__ S1, float* __restrict__ S2, float* __restrict__ ncnt) {
    int b = blockIdx.x >> 4;
    int chunk = blockIdx.x & 15;
    int wid = threadIdx.x >> 6, lane = threadIdx.x & 63;
    int c0 = lane << 2;
    float4 w4 = *reinterpret_cast<const float4*>(lnw + c0);
    float4 b4 = *reinterpret_cast<const float4*>(lnb + c0);
    float a1[4] = {0,0,0,0}, a2[4] = {0,0,0,0};
    int cnt = 0;
    int tbase = chunk * 512;
    for (int r = wid; r < 512; r += 4) {
        int row = b * T_ + tbase + r;
        float4 xv = *reinterpret_cast<const float4*>(x + (size_t)row * C_ + c0);
        float s1 = xv.x + xv.y + xv.z + xv.w;
        float s2 = xv.x*xv.x + xv.y*xv.y + xv.z*xv.z + xv.w*xv.w;
#pragma unroll
        for (int m = 1; m < 64; m <<= 1) { s1 += __shfl_xor(s1, m); s2 += __shfl_xor(s2, m); }
        if (mask[row]) {
            float mu = s1 * (1.f / C_);
            float var = s2 * (1.f / C_) - mu * mu;
            float rs = rsqrtf(var + 1e-5f);
            float hv;
            hv = (xv.x - mu) * rs * w4.x + b4.x; a1[0] += hv; a2[0] += hv * hv;
            hv = (xv.y - mu) * rs * w4.y + b4.y; a1[1] += hv; a2[1] += hv * hv;
            hv = (xv.z - mu) * rs * w4.z + b4.z; a1[2] += hv; a2[2] += hv * hv;
            hv = (xv.w - mu) * rs * w4.w + b4.w; a1[3] += hv; a2[3] += hv * hv;
            cnt++;
        }
    }
    __shared__ float red[4][256];
    __shared__ int rc[4];
#pragma unroll
    for (int j = 0; j < 4; j++) red[wid][c0 + j] = a1[j];
    if (lane == 0) rc[wid] = cnt;
    __syncthreads();
    int ch = threadIdx.x;
    float s = red[0][ch] + red[1][ch] + red[2][ch] + red[3][ch];
    atomicAdd(&S1[(b << 8) + ch], s);
    if (threadIdx.x == 0) atomicAdd(&ncnt[b], (float)(rc[0] + rc[1] + rc[2] + rc[3]));
    __syncthreads();
#pragma unroll
    for (int j = 0; j < 4; j++) red[wid][c0 + j] = a2[j];
    __syncthreads();
    s = red[0][ch] + red[1][ch] + red[2][ch] + red[3][ch];
    atomicAdd(&S2[(b << 8) + ch], s);
}

__global__ void k_stats_fin(const float* __restrict__ S1, const float* __restrict__ S2,
                            const float* __restrict__ ncnt, float* __restrict__ stats) {
    int b = blockIdx.x, c = threadIdx.x;
    float n = fmaxf(ncnt[b], 1.f);
    float mean = S1[(b << 8) + c] / n;
    float var_b = fmaxf(S2[(b << 8) + c] / n - mean * mean, 0.f);
    float var_u = (n > 1.f) ? (var_b * (n / fmaxf(n - 1.f, 1e-9f))) : var_b;
    float std_u = fmaxf(sqrtf(var_u), 1e-9f);
    stats[b * 768 + 0 * 256 + c] = mean;
    stats[b * 768 + 1 * 256 + c] = std_u;
    stats[b * 768 + 2 * 256 + c] = var_u;
}

__global__ void k_bias(const float* __restrict__ W1, const float* __restrict__ b1,
                       const float* __restrict__ stats, float* __restrict__ bias) {
    int b = blockIdx.x >> 3, e = blockIdx.x & 7, c = threadIdx.x;
    __shared__ float sm[768];
    for (int i = threadIdx.x; i < 768; i += 256) sm[i] = stats[b * 768 + i];
    __syncthreads();
    const float* w = W1 + (size_t)e * 1024 * 256;
    float acc = b1[(e << 8) + c];
#pragma unroll 4
    for (int j = 0; j < 256; j++) {
        acc += sm[j]       * w[(256 + j) * 256 + c];
        acc += sm[256 + j] * w[(512 + j) * 256 + c];
        acc += sm[512 + j] * w[(768 + j) * 256 + c];
    }
    bias[((b << 3) + e) * 256 + c] = acc;
}

// ---------------- energies: GEMM1(LDS-staged B) + gelu + dot(v2) ----------------

__global__ __launch_bounds__(256, 3) void k_energy(
    const unsigned short* __restrict__ xb, const unsigned short* __restrict__ w1t,
    const float* __restrict__ bias, const float* __restrict__ v2,
    const float* __restrict__ c2, float* __restrict__ energy) {
    __shared__ unsigned short bstage[2][8192];
    int row0 = blockIdx.x << 6;
    int b = row0 >> 13;
    int tid = threadIdx.x;
    int wid = tid >> 6, lane = tid & 63;
    int rlo = lane & 15, khi = lane >> 4;

    // A rows in registers (16 rows/wave), reused across all experts
    const unsigned short* arow = xb + (size_t)(row0 + (wid << 4) + rlo) * C_ + (khi << 3);
    bf16x8 areg[8];
#pragma unroll
    for (int kk = 0; kk < 8; kk++) areg[kk] = *reinterpret_cast<const bf16x8*>(arow + (kk << 5));

    stage16k(w1t, &bstage[0][0], tid);
    __syncthreads();

    int pc = 0;
    for (int e = 0; e < E_; e++) {
        const float* bre = bias + ((b << 3) + e) * C_;
        f32x4 acc[16];
#pragma unroll
        for (int n = 0; n < 16; n++) {
            float bv = bre[(n << 4) + rlo];
#pragma unroll
            for (int i = 0; i < 4; i++) acc[n][i] = bv;
        }
#pragma unroll
        for (int kk = 0; kk < 8; kk++) {
            int half = pc & 1;
            int nc = pc + 1;
            if (nc < 64) {
                const unsigned short* nsrc = w1t + ((nc >> 3) << 16) + ((nc & 7) << 5);
                stage16k(nsrc, &bstage[half ^ 1][0], tid);
            }
            const unsigned short* bs = &bstage[half][0];
            bf16x8 a = areg[kk];
#pragma unroll
            for (int n = 0; n < 16; n++) {
                bf16x8 bf = *reinterpret_cast<const bf16x8*>(bs + ((((n << 4) + rlo)) << 5) + (khi << 3));
                acc[n] = mfma16(a, bf, acc[n]);
            }
            __syncthreads();
            pc++;
        }
        float ep[4] = {0,0,0,0};
#pragma unroll
        for (int n = 0; n < 16; n++) {
            float vv = v2[(e << 8) + (n << 4) + rlo];
#pragma unroll
            for (int i = 0; i < 4; i++) ep[i] += gelu_f(acc[n][i]) * vv;
        }
#pragma unroll
        for (int m = 1; m < 16; m <<= 1) {
#pragma unroll
            for (int i = 0; i < 4; i++) ep[i] += __shfl_xor(ep[i], m);
        }
        if (rlo == 0) {
            float cc = c2[e];
#pragma unroll
            for (int i = 0; i < 4; i++)
                energy[(size_t)(row0 + (wid << 4) + (khi << 2) + i) * E_ + e] = ep[i] + cc;
        }
    }
}

// ---------------- output: softmax + GEMM1 + gelu + scale + GEMM2 (LDS-staged B) ----------------

__global__ __launch_bounds__(256, 2) void k_out(
    const unsigned short* __restrict__ xb, const unsigned short* __restrict__ w1t,
    const unsigned short* __restrict__ w2t, const float* __restrict__ bias,
    const float* __restrict__ energy, const int* __restrict__ mask,
    const float* __restrict__ b2, const float* __restrict__ log_beta,
    const float* __restrict__ prior, float* __restrict__ out) {
    __shared__ unsigned short bstage[2][8192];
    __shared__ unsigned short h1_s[4][4096];
    __shared__ float probs_s[64][8];
    __shared__ float b2_s[8][256];
    int row0 = blockIdx.x << 6;
    int b = row0 >> 13;
    int tid = threadIdx.x;
    for (int i = tid; i < 2048; i += 256) (&b2_s[0][0])[i] = b2[i];
    if (tid < 64) {
        int row = row0 + tid;
        float beta = __expf(log_beta[0]);
        float nb[8]; float mx = -3.4e38f;
#pragma unroll
        for (int e = 0; e < 8; e++) {
            nb[e] = -beta * (energy[(size_t)row * 8 + e] + prior[e]);
            mx = fmaxf(mx, nb[e]);
        }
        float s = 0.f; float pe[8];
#pragma unroll
        for (int e = 0; e < 8; e++) { pe[e] = __expf(nb[e] - mx); s += pe[e]; }
        float inv = mask[row] ? (1.f / s) : 0.f;
#pragma unroll
        for (int e = 0; e < 8; e++) probs_s[tid][e] = pe[e] * inv;
    }
    int wid = tid >> 6, lane = tid & 63;
    int rlo = lane & 15, khi = lane >> 4;
    unsigned short* h1w = h1_s[wid];

    const unsigned short* arow = xb + (size_t)(row0 + (wid << 4) + rlo) * C_ + (khi << 3);
    bf16x8 areg[8];
#pragma unroll
    for (int kk = 0; kk < 8; kk++) areg[kk] = *reinterpret_cast<const bf16x8*>(arow + (kk << 5));

    f32x4 acc2[16];
#pragma unroll
    for (int n = 0; n < 16; n++)
#pragma unroll
        for (int i = 0; i < 4; i++) acc2[n][i] = 0.f;

    stage16k(w1t, &bstage[0][0], tid);
    __syncthreads();

    int pc = 0;
    for (int e = 0; e < E_; e++) {
        const float* bre = bias + ((b << 3) + e) * C_;
        f32x4 acc1[16];
#pragma unroll
        for (int n = 0; n < 16; n++) {
            float bv = bre[(n << 4) + rlo];
#pragma unroll
            for (int i = 0; i < 4; i++) acc1[n][i] = bv;
        }
        // GEMM1: 8 staged phases
#pragma unroll
        for (int kk = 0; kk < 8; kk++) {
            int half = pc & 1;
            int nc = pc + 1;
            if (nc < 128) {
                int ne = nc >> 4, ng = (nc >> 3) & 1, nk = nc & 7;
                const unsigned short* nsrc = (ng ? w2t : w1t) + (ne << 16) + (nk << 5);
                stage16k(nsrc, &bstage[half ^ 1][0], tid);
            }
            const unsigned short* bs = &bstage[half][0];
            bf16x8 a = areg[kk];
#pragma unroll
            for (int n = 0; n < 16; n++) {
                bf16x8 bf = *reinterpret_cast<const bf16x8*>(bs + (((n << 4) + rlo) << 5) + (khi << 3));
                acc1[n] = mfma16(a, bf, acc1[n]);
            }
            __syncthreads();
            pc++;
        }
        // scaled gelu(h1) -> per-wave LDS slice (XOR-swizzled rows)
        float pv[4];
#pragma unroll
        for (int i = 0; i < 4; i++) pv[i] = probs_s[(wid << 4) + (khi << 2) + i][e];
#pragma unroll
        for (int n = 0; n < 16; n++) {
#pragma unroll
            for (int i = 0; i < 4; i++) {
                int row_l = (khi << 2) + i;
                int col = (n << 4) + rlo;
                int byteoff = ((row_l << 9) + (col << 1)) ^ ((row_l & 7) << 4);
                *reinterpret_cast<unsigned short*>(reinterpret_cast<char*>(h1w) + byteoff)
                    = f2bf(gelu_f(acc1[n][i]) * pv[i]);
            }
        }
        // GEMM2: 8 staged phases, A from swizzled h1
#pragma unroll
        for (int kk = 0; kk < 8; kk++) {
            int half = pc & 1;
            int nc = pc + 1;
            if (nc < 128) {
                int ne = nc >> 4, ng = (nc >> 3) & 1, nk = nc & 7;
                const unsigned short* nsrc = (ng ? w2t : w1t) + (ne << 16) + (nk << 5);
                stage16k(nsrc, &bstage[half ^ 1][0], tid);
            }
            const unsigned short* bs = &bstage[half][0];
            int byteoff = ((rlo << 9) + (kk << 6) + (khi << 4)) ^ ((rlo & 7) << 4);
            bf16x8 a2 = *reinterpret_cast<const bf16x8*>(reinterpret_cast<char*>(h1w) + byteoff);
#pragma unroll
            for (int n = 0; n < 16; n++) {
                bf16x8 bf = *reinterpret_cast<const bf16x8*>(bs + (((n << 4) + rlo) << 5) + (khi << 3));
                acc2[n] = mfma16(a2, bf, acc2[n]);
            }
            __syncthreads();
            pc++;
        }
    }
    // epilogue: + sum_e probs*b2, write (masked rows have probs==0 -> exact 0)
    float pr[4][8];
#pragma unroll
    for (int i = 0; i < 4; i++) {
        int row_l = (wid << 4) + (khi << 2) + i;
#pragma unroll
        for (int e = 0; e < 8; e++) pr[i][e] = probs_s[row_l][e];
    }
#pragma unroll
    for (int n = 0; n < 16; n++) {
        int col = (n << 4) + rlo;
        float bc[8];
#pragma unroll
        for (int e = 0; e < 8; e++) bc[e] = b2_s[e][col];
#pragma unroll
        for (int i = 0; i < 4; i++) {
            float o = acc2[n][i];
#pragma unroll
            for (int e = 0; e < 8; e++) o += pr[i][e] * bc[e];
            out[(size_t)(row0 + (wid << 4) + (khi << 2) + i) * C_ + col] = o;
        }
    }
}

// ---------------- launch ----------------

extern "C" void kernel_launch(void* const* d_in, const int* in_sizes, int n_in,
                              void* d_out, int out_size, void* d_ws, size_t ws_size,
                              hipStream_t stream) {
    (void)in_sizes; (void)n_in; (void)out_size; (void)ws_size;
    const float* x        = (const float*)d_in[0];
    const int*   mask     = (const int*)d_in[1];
    const float* lnw      = (const float*)d_in[2];
    const float* lnb      = (const float*)d_in[3];
    const float* W1       = (const float*)d_in[4];
    const float* b1       = (const float*)d_in[5];
    const float* W2       = (const float*)d_in[6];
    const float* b2       = (const float*)d_in[7];
    const float* We       = (const float*)d_in[8];
    const float* be       = (const float*)d_in[9];
    const float* log_beta = (const float*)d_in[10];
    const float* prior    = (const float*)d_in[11];
    float* out = (float*)d_out;
    char* ws = (char*)d_ws;

    constexpr size_t OFF_XB    = 0;                       // 16 MB
    constexpr size_t OFF_W1T   = 16777216;                // 1 MB
    constexpr size_t OFF_W2T   = 17825792;                // 1 MB
    constexpr size_t OFF_V2    = 18874368;                // 8 KB
    constexpr size_t OFF_C2    = 18882560;                // 32 B
    constexpr size_t OFF_S1    = 18882592;                // 4 KB
    constexpr size_t OFF_S2    = 18886688;                // 4 KB
    constexpr size_t OFF_N     = 18890784;                // 16 B
    constexpr size_t OFF_STATS = 18890800;                // 12 KB
    constexpr size_t OFF_BIAS  = 18903088;                // 32 KB
    constexpr size_t OFF_EN    = 18935856;                // 1 MB

    unsigned short* xb  = (unsigned short*)(ws + OFF_XB);
    unsigned short* w1t = (unsigned short*)(ws + OFF_W1T);
    unsigned short* w2t = (unsigned short*)(ws + OFF_W2T);
    float* v2    = (float*)(ws + OFF_V2);
    float* c2    = (float*)(ws + OFF_C2);
    float* S1    = (float*)(ws + OFF_S1);
    float* S2    = (float*)(ws + OFF_S2);
    float* ncnt  = (float*)(ws + OFF_N);
    float* stats = (float*)(ws + OFF_STATS);
    float* bias  = (float*)(ws + OFF_BIAS);
    float* en    = (float*)(ws + OFF_EN);

    hipMemsetAsync(ws + OFF_S1, 0, 4096 + 4096 + 16, stream);

    k_cvt_x<<<8192, 256, 0, stream>>>(x, xb);
    k_w1t<<<128, 256, 0, stream>>>(W1, w1t);
    k_w2t<<<128, 256, 0, stream>>>(W2, w2t);
    k_v2<<<2048, 256, 0, stream>>>(W2, We, b2, be, v2, c2);
    k_stats<<<64, 256, 0, stream>>>(x, mask, lnw, lnb, S1, S2, ncnt);
    k_stats_fin<<<4, 256, 0, stream>>>(S1, S2, ncnt, stats);
    k_bias<<<32, 256, 0, stream>>>(W1, b1, stats, bias);
    k_energy<<<512, 256, 0, stream>>>(xb, w1t, bias, v2, c2, en);
    k_out<<<512, 256, 0, stream>>>(xb, w1t, w2t, bias, en, mask, b2, log_beta, prior, out);
}